// Round 6
// baseline (99.074 us; speedup 1.0000x reference)
//
#include <hip/hip_runtime.h>

#define BLOCK 256
#define GRID_BLOCKS 1536   // 6 blocks/CU x 256 CUs, all co-resident (23KB LDS/block)

// Persistent grid-stride expm kernel with register prefetch.
//   A = [[M, t],[0,...,0]]  =>  exp(A) = [[R, p],[0,0,0,1]], T[3][3]==1 exactly
// Pade(3,3) + wave-uniform scaling-and-squaring, fp32 (tolerance 1.77, we land ~0.06).
// Pipeline per tile: barrier A -> prefetch next tile (global->regs, latency hidden
// under compute) -> ds_read+compute -> shOut write -> barrier B -> b128 stores.
// Stores of tile t overlap staging/compute of tile t+1 (fire-and-forget).
__global__ __launch_bounds__(BLOCK, 6) void lie_expm_kernel(
    const float* __restrict__ in, float* __restrict__ out, int B)
{
    __shared__ float shIn[BLOCK * 7];     // 7 KB input staging
    __shared__ float shOut[BLOCK * 16];   // 16 KB output staging
    const int tid = threadIdx.x;
    const int numTiles = (B + BLOCK - 1) / BLOCK;
    const long long totF = (long long)B * 7;        // total input floats
    const long long TOT4 = totF >> 2;               // whole float4s
    const float4* __restrict__ in4 = (const float4*)in;

    // ---- prologue: prefetch first tile into registers ----
    int t = blockIdx.x;
    float4 r0, r1;
    {
        const long long base4 = (long long)t * (BLOCK * 7 / 4);  // 448 f4/tile
        long long i0 = base4 + tid;
        long long i1 = base4 + BLOCK + tid;
        r0 = in4[i0 < TOT4 ? i0 : TOT4 - 1];
        r1 = in4[i1 < TOT4 ? i1 : TOT4 - 1];
    }

    for (; t < numTiles; t += GRID_BLOCKS) {
        const long long tileBase = (long long)t * BLOCK;

        // ---- stage current tile from prefetch regs ----
        {
            float4* s4 = (float4*)shIn;
            s4[tid] = r0;
            if (tid < BLOCK * 7 / 4 - BLOCK) s4[BLOCK + tid] = r1;  // tid < 192
        }
        // generic-B scalar tail (input floats not a multiple of 4): last tile only
        if ((totF & 3LL) && t == numTiles - 1) {
            const long long firstMissing = TOT4 << 2;          // global float idx
            const int nmiss = (int)(totF - firstMissing);      // 1..3
            const int loc = (int)(firstMissing - tileBase * 7);
            if (tid < nmiss && loc + tid < BLOCK * 7)
                shIn[loc + tid] = in[firstMissing + tid];
        }
        __syncthreads();   // barrier A: shIn(t) visible; shOut(t-1) fully consumed

        // ---- prefetch next tile (latency hides under compute below) ----
        {
            const int tn = t + GRID_BLOCKS;
            if (tn < numTiles) {
                const long long base4 = (long long)tn * (BLOCK * 7 / 4);
                long long i0 = base4 + tid;
                long long i1 = base4 + BLOCK + tid;
                r0 = in4[i0 < TOT4 ? i0 : TOT4 - 1];
                r1 = in4[i1 < TOT4 ? i1 : TOT4 - 1];
            }
        }

        // ---- per-thread expm ----
        const float v0 = shIn[tid * 7 + 0];
        const float v1 = shIn[tid * 7 + 1];
        const float v2 = shIn[tid * 7 + 2];
        const float v3 = shIn[tid * 7 + 3];
        const float v4 = shIn[tid * 7 + 4];
        const float v5 = shIn[tid * 7 + 5];
        const float v6 = shIn[tid * 7 + 6];

        float X[3][4] = {
            {  v6, -v5,  v4, v0 },
            {  v5, -v6, -v3, v1 },
            { -v4,  v3, 0.0f, v2 }
        };

        // inf-norm -> wave-max -> uniform s with scaled norm < 0.5
        float n0 = fabsf(X[0][0]) + fabsf(X[0][1]) + fabsf(X[0][2]) + fabsf(X[0][3]);
        float n1 = fabsf(X[1][0]) + fabsf(X[1][1]) + fabsf(X[1][2]) + fabsf(X[1][3]);
        float n2 = fabsf(X[2][0]) + fabsf(X[2][1]) + fabsf(X[2][2]) + fabsf(X[2][3]);
        float nrm = fmaxf(n0, fmaxf(n1, n2));
        #pragma unroll
        for (int off = 32; off >= 1; off >>= 1)
            nrm = fmaxf(nrm, __shfl_xor(nrm, off, 64));
        int e = (int)((__float_as_uint(nrm) >> 23) & 0xFFu) - 126;
        int s = min(max(e + 1, 0), 8);
        s = __builtin_amdgcn_readfirstlane(s);
        const float sc = __uint_as_float((unsigned)(127 - s) << 23); // exact 2^-s

        #pragma unroll
        for (int i = 0; i < 3; i++)
            #pragma unroll
            for (int c = 0; c < 4; c++)
                X[i][c] *= sc;

        // A2 = A*A (A's last row is zero)
        float A2[3][4];
        #pragma unroll
        for (int i = 0; i < 3; i++) {
            #pragma unroll
            for (int c = 0; c < 4; c++) {
                float acc = X[i][0] * X[0][c];
                acc = fmaf(X[i][1], X[1][c], acc);
                acc = fmaf(X[i][2], X[2][c], acc);
                A2[i][c] = acc;
            }
        }

        // Pade(3,3): U = A*(I/2 + A2/120), V = I + A2/10; N=V+U, D=V-U
        const float c120 = 1.0f / 120.0f;
        const float c10  = 0.1f;
        float W[3][4];
        #pragma unroll
        for (int i = 0; i < 3; i++)
            #pragma unroll
            for (int c = 0; c < 4; c++)
                W[i][c] = fmaf(A2[i][c], c120, (i == c) ? 0.5f : 0.0f);

        float Nm[3][4], Dm[3][4];
        #pragma unroll
        for (int i = 0; i < 3; i++) {
            #pragma unroll
            for (int c = 0; c < 4; c++) {
                float u = (c == 3) ? 0.5f * X[i][3] : 0.0f; // W implicit row3 = [0,0,0,0.5]
                u = fmaf(X[i][0], W[0][c], u);
                u = fmaf(X[i][1], W[1][c], u);
                u = fmaf(X[i][2], W[2][c], u);
                float v = fmaf(A2[i][c], c10, (i == c) ? 1.0f : 0.0f);
                Nm[i][c] = v + u;
                Dm[i][c] = v - u;
            }
        }

        // D3^-1 via adjugate (D ~ I, well-conditioned)
        const float d00 = Dm[0][0], d01 = Dm[0][1], d02 = Dm[0][2];
        const float d10 = Dm[1][0], d11 = Dm[1][1], d12 = Dm[1][2];
        const float d20 = Dm[2][0], d21 = Dm[2][1], d22 = Dm[2][2];
        const float a00 = fmaf(d11, d22, -d12 * d21);
        const float a01 = fmaf(d02, d21, -d01 * d22);
        const float a02 = fmaf(d01, d12, -d02 * d11);
        const float a10 = fmaf(d12, d20, -d10 * d22);
        const float a11 = fmaf(d00, d22, -d02 * d20);
        const float a12 = fmaf(d02, d10, -d00 * d12);
        const float a20 = fmaf(d10, d21, -d11 * d20);
        const float a21 = fmaf(d01, d20, -d00 * d21);
        const float a22 = fmaf(d00, d11, -d01 * d10);
        float det = d00 * a00 + d01 * a10 + d02 * a20;
        float r = __builtin_amdgcn_rcpf(det);
        r = r * fmaf(-det, r, 2.0f);  // one Newton step
        const float i00 = a00 * r, i01 = a01 * r, i02 = a02 * r;
        const float i10 = a10 * r, i11 = a11 * r, i12 = a12 * r;
        const float i20 = a20 * r, i21 = a21 * r, i22 = a22 * r;

        // P = D^-1 * N (cols 0..2); col 3: p = D3^-1 * (n - d)
        float P[3][4];
        float rhs0 = Nm[0][3] - Dm[0][3], rhs1 = Nm[1][3] - Dm[1][3], rhs2 = Nm[2][3] - Dm[2][3];
        #pragma unroll
        for (int c = 0; c < 3; c++) {
            P[0][c] = i00 * Nm[0][c] + i01 * Nm[1][c] + i02 * Nm[2][c];
            P[1][c] = i10 * Nm[0][c] + i11 * Nm[1][c] + i12 * Nm[2][c];
            P[2][c] = i20 * Nm[0][c] + i21 * Nm[1][c] + i22 * Nm[2][c];
        }
        P[0][3] = i00 * rhs0 + i01 * rhs1 + i02 * rhs2;
        P[1][3] = i10 * rhs0 + i11 * rhs1 + i12 * rhs2;
        P[2][3] = i20 * rhs0 + i21 * rhs1 + i22 * rhs2;

        // s squarings, wave-uniform trip count (implicit last row [0,0,0,1])
        for (int q = 0; q < s; q++) {
            float T[3][4];
            #pragma unroll
            for (int i = 0; i < 3; i++) {
                #pragma unroll
                for (int c = 0; c < 4; c++) {
                    float acc = (c == 3) ? P[i][3] : 0.0f;
                    acc = fmaf(P[i][0], P[0][c], acc);
                    acc = fmaf(P[i][1], P[1][c], acc);
                    acc = fmaf(P[i][2], P[2][c], acc);
                    T[i][c] = acc;
                }
            }
            #pragma unroll
            for (int i = 0; i < 3; i++)
                #pragma unroll
                for (int c = 0; c < 4; c++)
                    P[i][c] = T[i][c];
        }

        // ---- output restage (quad-rotated, conflict-free b128) ----
        {
            float4* s4 = (float4*)shOut;
            const int rot = (tid >> 1) & 3;
            #pragma unroll
            for (int i = 0; i < 4; i++) {
                const int qp = (i + rot) & 3;
                float4 q;
                if (i < 3) q = make_float4(P[i][0], P[i][1], P[i][2], P[i][3]);
                else       q = make_float4(0.0f, 0.0f, 0.0f, 1.0f);
                s4[tid * 4 + qp] = q;
            }
        }
        __syncthreads();   // barrier B: shOut ready; all shIn reads done

        // ---- fully-coalesced float4 stores (overlap next iter's staging) ----
        {
            const float4* s4 = (const float4*)shOut;
            float4* out4 = (float4*)(out + tileBase * 16);
            long long vq = ((long long)B - tileBase) * 4;
            const int validquads = (vq > BLOCK * 4) ? (BLOCK * 4) : (int)vq;
            #pragma unroll
            for (int it = 0; it < 4; it++) {
                const int g = it * BLOCK + tid;
                const int row = g >> 2, k = g & 3;
                const float4 val = s4[(row << 2) | ((k + ((row >> 1) & 3)) & 3)];
                if (g < validquads) out4[g] = val;
            }
        }
    }
}

extern "C" void kernel_launch(void* const* d_in, const int* in_sizes, int n_in,
                              void* d_out, int out_size, void* d_ws, size_t ws_size,
                              hipStream_t stream) {
    const float* in = (const float*)d_in[0];
    float* out = (float*)d_out;
    const int B = in_sizes[0] / 7;
    const int numTiles = (B + BLOCK - 1) / BLOCK;
    const int grid = (numTiles < GRID_BLOCKS) ? numTiles : GRID_BLOCKS;
    lie_expm_kernel<<<grid, BLOCK, 0, stream>>>(in, out, B);
}

// Round 7
// 89.456 us; speedup vs baseline: 1.1075x; 1.1075x over previous
//
#include <hip/hip_runtime.h>

#define BLOCK 256

// Per-thread 4x4 expm of A = sum v_k E_k, exploiting A's zero last row:
//   A = [[M, t],[0,...,0]]  =>  exp(A) = [[R, p],[0,0,0,1]], T[3][3]==1 exactly
// so the homogeneous normalization is a no-op. Carry only the top 3x4 block.
//
// Math: Pade(3,3) + scaling-and-squaring in fp32, wave-uniform squaring count
// (wave-max norm -> readfirstlane -> scalar loop, zero divergence).
// Tolerance is 1.77 absmax; this path lands ~0.06.
//
// Memory: all global traffic as b128 (float4). Outputs restaged through LDS
// with a quad-rotation layout (qp = (i + (t>>1)) & 3), conflict-free on both
// the ds_write_b128 and ds_read_b128 sides; then lane-consecutive float4
// stores (1 KB/wave-instr, minimum line traffic).
//
// R6 lesson: persistent-grid + register prefetch + launch_bounds(256,6)
// REGRESSED (+10 us) -- register squeeze + loop overhead with only ~2.5
// tiles/block of pipeline depth. This is the R5 structure (best measured).
__global__ __launch_bounds__(BLOCK) void lie_expm_kernel(
    const float* __restrict__ in, float* __restrict__ out, int B)
{
    __shared__ float sh[BLOCK * 16];   // 16 KB: input staging, then output staging
    const int tid = threadIdx.x;
    const long long blockBase = (long long)blockIdx.x * BLOCK;
    const bool fullBlock = (B - (int)blockBase) >= BLOCK;  // wave-uniform

    // ---- input staging: (BLOCK,7) fp32, vectorized float4 loads ----
    if (fullBlock) {
        // common case: exactly 448 float4s, no tail, no zero-fill
        const float4* in4 = (const float4*)(in + blockBase * 7);  // 7168B/block => 16B aligned
        float4* sh4 = (float4*)sh;
        sh4[tid] = in4[tid];
        if (tid < BLOCK * 7 / 4 - BLOCK) sh4[BLOCK + tid] = in4[BLOCK + tid];  // tid < 192
    } else {
        // last partial block only
        const int valid = B - (int)blockBase;
        const int limit = valid * 7;
        const int nf4 = limit >> 2;
        const float4* in4 = (const float4*)(in + blockBase * 7);
        float4* sh4 = (float4*)sh;
        #pragma unroll
        for (int it = 0; it < 2; ++it) {
            const int idx = it * BLOCK + tid;
            if (idx < nf4) sh4[idx] = in4[idx];
        }
        const int remf = limit & 3;
        if (tid < remf) sh[nf4 * 4 + tid] = in[blockBase * 7 + nf4 * 4 + tid];
        #pragma unroll
        for (int it = 0; it < 7; ++it) {
            const int i = it * BLOCK + tid;
            if (i >= limit && i < BLOCK * 7) sh[i] = 0.0f;   // expm(0)=I harmless
        }
    }
    __syncthreads();

    const float v0 = sh[tid * 7 + 0];
    const float v1 = sh[tid * 7 + 1];
    const float v2 = sh[tid * 7 + 2];
    const float v3 = sh[tid * 7 + 3];
    const float v4 = sh[tid * 7 + 4];
    const float v5 = sh[tid * 7 + 5];
    const float v6 = sh[tid * 7 + 6];

    // top 3 rows of A
    float X[3][4] = {
        {  v6, -v5,  v4, v0 },
        {  v5, -v6, -v3, v1 },
        { -v4,  v3, 0.0f, v2 }
    };

    // inf-norm -> wave-max -> uniform s with scaled norm < 0.5
    float n0 = fabsf(X[0][0]) + fabsf(X[0][1]) + fabsf(X[0][2]) + fabsf(X[0][3]);
    float n1 = fabsf(X[1][0]) + fabsf(X[1][1]) + fabsf(X[1][2]) + fabsf(X[1][3]);
    float n2 = fabsf(X[2][0]) + fabsf(X[2][1]) + fabsf(X[2][2]) + fabsf(X[2][3]);
    float nrm = fmaxf(n0, fmaxf(n1, n2));
    #pragma unroll
    for (int off = 32; off >= 1; off >>= 1)
        nrm = fmaxf(nrm, __shfl_xor(nrm, off, 64));
    int e = (int)((__float_as_uint(nrm) >> 23) & 0xFFu) - 126;  // nrm in [2^(e-1), 2^e)
    int s = min(max(e + 1, 0), 8);                              // nrm/2^s < 0.5
    s = __builtin_amdgcn_readfirstlane(s);                      // SGPR: uniform loop bound
    const float sc = __uint_as_float((unsigned)(127 - s) << 23); // exact 2^-s

    #pragma unroll
    for (int i = 0; i < 3; i++)
        #pragma unroll
        for (int c = 0; c < 4; c++)
            X[i][c] *= sc;

    // A2 = A*A  (A's last row is zero)
    float A2[3][4];
    #pragma unroll
    for (int i = 0; i < 3; i++) {
        #pragma unroll
        for (int c = 0; c < 4; c++) {
            float acc = X[i][0] * X[0][c];
            acc = fmaf(X[i][1], X[1][c], acc);
            acc = fmaf(X[i][2], X[2][c], acc);
            A2[i][c] = acc;
        }
    }

    // Pade(3,3): U = A*(I/2 + A2/120) (odd), V = I + A2/10 (even); N=V+U, D=V-U
    const float c120 = 1.0f / 120.0f;
    const float c10  = 0.1f;
    float W[3][4];
    #pragma unroll
    for (int i = 0; i < 3; i++)
        #pragma unroll
        for (int c = 0; c < 4; c++)
            W[i][c] = fmaf(A2[i][c], c120, (i == c) ? 0.5f : 0.0f);

    float Nm[3][4], Dm[3][4];
    #pragma unroll
    for (int i = 0; i < 3; i++) {
        #pragma unroll
        for (int c = 0; c < 4; c++) {
            float u = (c == 3) ? 0.5f * X[i][3] : 0.0f;  // W implicit last row [0,0,0,0.5]
            u = fmaf(X[i][0], W[0][c], u);
            u = fmaf(X[i][1], W[1][c], u);
            u = fmaf(X[i][2], W[2][c], u);
            float v = fmaf(A2[i][c], c10, (i == c) ? 1.0f : 0.0f);
            Nm[i][c] = v + u;
            Dm[i][c] = v - u;
        }
    }

    // Invert D3 (3x3 block) via adjugate; D ~ I, well-conditioned.
    const float d00 = Dm[0][0], d01 = Dm[0][1], d02 = Dm[0][2];
    const float d10 = Dm[1][0], d11 = Dm[1][1], d12 = Dm[1][2];
    const float d20 = Dm[2][0], d21 = Dm[2][1], d22 = Dm[2][2];
    const float a00 = fmaf(d11, d22, -d12 * d21);
    const float a01 = fmaf(d02, d21, -d01 * d22);
    const float a02 = fmaf(d01, d12, -d02 * d11);
    const float a10 = fmaf(d12, d20, -d10 * d22);
    const float a11 = fmaf(d00, d22, -d02 * d20);
    const float a12 = fmaf(d02, d10, -d00 * d12);
    const float a20 = fmaf(d10, d21, -d11 * d20);
    const float a21 = fmaf(d01, d20, -d00 * d21);
    const float a22 = fmaf(d00, d11, -d01 * d10);
    float det = d00 * a00 + d01 * a10 + d02 * a20;
    float r = __builtin_amdgcn_rcpf(det);
    r = r * fmaf(-det, r, 2.0f);  // one Newton step
    const float i00 = a00 * r, i01 = a01 * r, i02 = a02 * r;
    const float i10 = a10 * r, i11 = a11 * r, i12 = a12 * r;
    const float i20 = a20 * r, i21 = a21 * r, i22 = a22 * r;

    // P = D^-1 * N (cols 0..2); col 3: p = D3^-1 * (n - d)
    float P[3][4];
    float rhs0 = Nm[0][3] - Dm[0][3], rhs1 = Nm[1][3] - Dm[1][3], rhs2 = Nm[2][3] - Dm[2][3];
    #pragma unroll
    for (int c = 0; c < 3; c++) {
        P[0][c] = i00 * Nm[0][c] + i01 * Nm[1][c] + i02 * Nm[2][c];
        P[1][c] = i10 * Nm[0][c] + i11 * Nm[1][c] + i12 * Nm[2][c];
        P[2][c] = i20 * Nm[0][c] + i21 * Nm[1][c] + i22 * Nm[2][c];
    }
    P[0][3] = i00 * rhs0 + i01 * rhs1 + i02 * rhs2;
    P[1][3] = i10 * rhs0 + i11 * rhs1 + i12 * rhs2;
    P[2][3] = i20 * rhs0 + i21 * rhs1 + i22 * rhs2;

    // s squarings, wave-uniform trip count (implicit last row [0,0,0,1])
    for (int q = 0; q < s; q++) {
        float T[3][4];
        #pragma unroll
        for (int i = 0; i < 3; i++) {
            #pragma unroll
            for (int c = 0; c < 4; c++) {
                float acc = (c == 3) ? P[i][3] : 0.0f;
                acc = fmaf(P[i][0], P[0][c], acc);
                acc = fmaf(P[i][1], P[1][c], acc);
                acc = fmaf(P[i][2], P[2][c], acc);
                T[i][c] = acc;
            }
        }
        #pragma unroll
        for (int i = 0; i < 3; i++)
            #pragma unroll
            for (int c = 0; c < 4; c++)
                P[i][c] = T[i][c];
    }

    // ---- output restage (quad-rotated, conflict-free b128) ----
    __syncthreads();  // WAR: input staging reads complete
    {
        float4* sh4 = (float4*)sh;
        const int rot = (tid >> 1) & 3;
        #pragma unroll
        for (int i = 0; i < 4; i++) {
            const int qp = (i + rot) & 3;
            float4 q;
            if (i < 3) q = make_float4(P[i][0], P[i][1], P[i][2], P[i][3]);
            else       q = make_float4(0.0f, 0.0f, 0.0f, 1.0f);
            sh4[tid * 4 + qp] = q;
        }
    }
    __syncthreads();

    // ---- fully-coalesced float4 stores ----
    {
        const float4* sh4 = (const float4*)sh;
        float4* out4 = (float4*)(out + blockBase * 16);
        if (fullBlock) {
            #pragma unroll
            for (int it = 0; it < 4; it++) {
                const int g = it * BLOCK + tid;
                const int row = g >> 2, k = g & 3;
                out4[g] = sh4[(row << 2) | ((k + ((row >> 1) & 3)) & 3)];
            }
        } else {
            const int validquads = (B - (int)blockBase) * 4;
            #pragma unroll
            for (int it = 0; it < 4; it++) {
                const int g = it * BLOCK + tid;
                const int row = g >> 2, k = g & 3;
                const float4 val = sh4[(row << 2) | ((k + ((row >> 1) & 3)) & 3)];
                if (g < validquads) out4[g] = val;
            }
        }
    }
}

extern "C" void kernel_launch(void* const* d_in, const int* in_sizes, int n_in,
                              void* d_out, int out_size, void* d_ws, size_t ws_size,
                              hipStream_t stream) {
    const float* in = (const float*)d_in[0];
    float* out = (float*)d_out;
    const int B = in_sizes[0] / 7;
    const int grid = (B + BLOCK - 1) / BLOCK;
    lie_expm_kernel<<<grid, BLOCK, 0, stream>>>(in, out, B);
}